// Round 5
// baseline (15246.878 us; speedup 1.0000x reference)
//
#include <hip/hip_runtime.h>

#define EPS 1e-5f

__device__ __forceinline__ float logsig(float z) {
    return fminf(z, 0.0f) - log1pf(__expf(-fabsf(z)));
}

// One block = one sequence. 512 threads = 8 waves.
// Head h = wave&3; k-half kh = wave>>2 (each holds S[32] = rows kh*32..kh*32+31).
// PSTRIDE==1  : intra pass (seq over q, SLEN=128); PSTRIDE==128: inter pass (SLEN=256)
// NOTE: LDS = 155.5 KB pins occupancy at 1 block/CU, so launch_bounds min-occupancy
// MUST be 1 — asking for more only caps VGPRs (round 4: cap 128 -> spill storm).
template<int SLEN, int PSTRIDE>
__global__ __launch_bounds__(512, 1)
void gla_pass(const float* __restrict__ src, float* __restrict__ out,
              const float* __restrict__ gamma, const float* __restrict__ beta,
              const float* __restrict__ Wq, const float* __restrict__ Wk,
              const float* __restrict__ Wv, const float* __restrict__ Wg1,
              const float* __restrict__ Wg2, const float* __restrict__ Wr,
              const float* __restrict__ gn, const float* __restrict__ Wo,
              const float* __restrict__ ctw, const float* __restrict__ ctb)
{
    constexpr int NC = SLEN / 32;
    constexpr int L  = SLEN - 1;

    __shared__ __align__(16) float sxc[64][36];   // LN'd slab window (33 cols used)
    __shared__ __align__(16) float sxr[64][32];   // raw slab (residual source)
    __shared__ __align__(16) float qf[32][256];   // q*Dk^-0.5, then *exp(gc)
    __shared__ __align__(16) float kf[32][256];   // k, then *exp(-gc)
    __shared__ __align__(16) float voc[32][256];  // v -> oe1 partial -> o -> o*silu(r)
    __shared__ __align__(16) float uni[8832];     // Ats[4][32][36] + gdec[32][132]
    __shared__ __align__(16) float fw1t[32][36];  // (f @ Wg1)^T : fw1t[m][t]
    __shared__ __align__(16) float gprevs[128];   // deconv carry row
    __shared__ float egl[256];                    // exp(chunk-total gate)
    __shared__ float sgam[64], sbet[64];
    __shared__ float smu[33], sinv[33];
    __shared__ float gcarry[256];                 // gate cumsum carry (t=0..15 total)

    float* const Ats  = uni;          // h*1152 + t*36 + s
    float* const gdec = uni + 4608;   // row*132 + c

    const int tid  = threadIdx.x;
    const int lane = tid & 63;
    const int wv   = tid >> 6;        // 0..7
    const int h    = wv & 3;          // head
    const int kh   = wv >> 2;         // k-half
    const int d    = tid & 255;       // column for t-split stages
    const int th   = (tid >> 8) & 1;  // t-half (rows th*16 .. th*16+15)
    const int n    = blockIdx.x;

    int b, fixedoff;
    if constexpr (PSTRIDE == 1) { b = n >> 8; fixedoff = (n & 255) * 128; }
    else                        { b = n >> 7; fixedoff = (n & 127); }
    const int cbase = (b * 64) * 32768 + fixedoff;

    if (tid < 64)  { sgam[tid] = gamma[tid]; sbet[tid] = beta[tid]; }
    if (tid < 128) gprevs[tid] = 0.0f;

    float S[32];
    #pragma unroll
    for (int k = 0; k < 32; ++k) S[k] = 0.0f;

    const float gnv  = gn[h * 64 + lane];
    const float bias = ctb[lane];

    for (int ch = 0; ch < NC; ++ch) {
        const int l0 = ch * 32;
        __syncthreads();

        // ---- A: load 33-col slab window (raw copy kept for residual) ----
        for (int idx = tid; idx < 64 * 33; idx += 512) {
            int cc = idx / 33;
            int i  = idx - cc * 33;
            int p  = l0 + i; if (p > SLEN - 1) p = SLEN - 1;
            float x = src[cbase + cc * 32768 + p * PSTRIDE];
            sxc[cc][i] = x;
            if (i < 32) sxr[cc][i] = x;
        }
        __syncthreads();

        // ---- B1: per-column LN stats ----
        if (tid < 33) {
            float s1 = 0.0f, s2 = 0.0f;
            for (int cc = 0; cc < 64; ++cc) { float x = sxc[cc][tid]; s1 += x; s2 += x * x; }
            float mu = s1 * (1.0f / 64.0f);
            float var = s2 * (1.0f / 64.0f) - mu * mu;
            smu[tid]  = mu;
            sinv[tid] = rsqrtf(fmaxf(var, 0.0f) + EPS);
        }
        __syncthreads();
        // ---- B2: normalize in place (parallel) ----
        for (int idx = tid; idx < 64 * 33; idx += 512) {
            int cc = idx / 33;
            int i  = idx - cc * 33;
            sxc[cc][i] = (sxc[cc][i] - smu[i]) * sinv[i] * sgam[cc] + sbet[cc];
        }
        __syncthreads();

        // ---- C: fused q,k,v projections; thread = (col d, t-half th) ----
        {
            const int t0 = th * 16;
            float aq[16], ak[16], av[16];
            #pragma unroll
            for (int t = 0; t < 16; ++t) { aq[t] = 0.0f; ak[t] = 0.0f; av[t] = 0.0f; }
            for (int cc = 0; cc < 64; ++cc) {
                float col[17];
                #pragma unroll
                for (int i = 0; i < 4; ++i) {
                    float4 c4 = *(const float4*)&sxc[cc][t0 + 4 * i];
                    col[4*i] = c4.x; col[4*i+1] = c4.y; col[4*i+2] = c4.z; col[4*i+3] = c4.w;
                }
                col[16] = sxc[cc][t0 + 16];
                const float wq0 = Wq[(2*cc)*256 + d], wq1 = Wq[(2*cc+1)*256 + d];
                const float wk0 = Wk[(2*cc)*256 + d], wk1 = Wk[(2*cc+1)*256 + d];
                const float wv0 = Wv[(2*cc)*256 + d], wv1 = Wv[(2*cc+1)*256 + d];
                #pragma unroll
                for (int t = 0; t < 16; ++t) {
                    aq[t] += col[t] * wq0 + col[t+1] * wq1;
                    ak[t] += col[t] * wk0 + col[t+1] * wk1;
                    av[t] += col[t] * wv0 + col[t+1] * wv1;
                }
            }
            #pragma unroll
            for (int t = 0; t < 16; ++t) {
                bool valid = (l0 + t0 + t) < L;
                qf[t0 + t][d]  = valid ? aq[t] * 0.125f : 0.0f;
                kf[t0 + t][d]  = valid ? ak[t] : 0.0f;
                voc[t0 + t][d] = valid ? av[t] : 0.0f;
            }
        }

        // ---- gate p1: fw1t[m][t] ----
        {
            const int m = tid & 31, tg2 = tid >> 5;   // tg2 in [0,16)
            float a0 = 0.0f, a1 = 0.0f;
            for (int cc = 0; cc < 64; ++cc) {
                const float w0 = Wg1[(2*cc)*32 + m], w1 = Wg1[(2*cc+1)*32 + m];
                a0 += sxc[cc][tg2]      * w0 + sxc[cc][tg2 + 1]  * w1;
                a1 += sxc[cc][tg2 + 16] * w0 + sxc[cc][tg2 + 17] * w1;
            }
            fw1t[m][tg2] = a0; fw1t[m][tg2 + 16] = a1;
        }
        __syncthreads();

        // ---- gate p2: per (col d, t-half) cumsum with carry, fold into qf/kf ----
        {
            const int t0 = th * 16;
            float acc2[16];
            #pragma unroll
            for (int t = 0; t < 16; ++t) acc2[t] = 0.0f;
            for (int mm = 0; mm < 32; ++mm) {
                const float w = Wg2[mm * 256 + d];
                #pragma unroll
                for (int i = 0; i < 4; ++i) {
                    float4 f4 = *(const float4*)&fw1t[mm][t0 + 4 * i];
                    acc2[4*i+0] += f4.x * w; acc2[4*i+1] += f4.y * w;
                    acc2[4*i+2] += f4.z * w; acc2[4*i+3] += f4.w * w;
                }
            }
            float lrun[16]; float r = 0.0f;
            #pragma unroll
            for (int t = 0; t < 16; ++t) {
                if ((l0 + t0 + t) < L) r += logsig(acc2[t]) * (1.0f / 32.0f);
                lrun[t] = r;
            }
            if (th == 0) gcarry[d] = r;
            __syncthreads();
            const float c = (th == 0) ? 0.0f : gcarry[d];
            #pragma unroll
            for (int t = 0; t < 16; ++t) {
                float run = c + lrun[t];
                qf[t0 + t][d] *= __expf(run);
                kf[t0 + t][d] *= __expf(-run);
            }
            if (th == 1) egl[d] = __expf(c + lrun[15]);
        }
        __syncthreads();

        // ---- F: attention; 2 waves per head ----
        const int base = h * 64;
        float vcol[32];
        #pragma unroll
        for (int t = 0; t < 32; ++t) vcol[t] = voc[t][base + lane];

        // F1: triangular scores, 128 lanes per head
        for (int pi = lane + 64 * kh; pi < 528; pi += 128) {
            float fpi = (float)pi;
            int t = (int)((sqrtf(8.0f * fpi + 1.0f) - 1.0f) * 0.5f);
            if (((t + 1) * (t + 2)) / 2 <= pi) ++t;
            if ((t * (t + 1)) / 2 > pi) --t;
            int s = pi - (t * (t + 1)) / 2;
            float a = 0.0f;
            #pragma unroll
            for (int ii = 0; ii < 16; ++ii) {
                int i = (ii + lane) & 15;
                float4 q4 = *(const float4*)&qf[t][base + 4 * i];
                float4 k4 = *(const float4*)&kf[s][base + 4 * i];
                a += q4.x*k4.x + q4.y*k4.y + q4.z*k4.z + q4.w*k4.w;
            }
            Ats[h * 1152 + t * 36 + s] = a;
        }
        __syncthreads();   // Ats ready; all vcol snapshots done

        // F2a: o_inter partials vs pre-update S; then F4 state update (own half)
        float o0[32];
        if (kh == 1) {
            #pragma unroll
            for (int t = 0; t < 32; ++t) {
                float oe = 0.0f;
                #pragma unroll
                for (int i = 0; i < 8; ++i) {
                    float4 q4 = *(const float4*)&qf[t][base + 32 + 4 * i];
                    oe += q4.x*S[4*i] + q4.y*S[4*i+1] + q4.z*S[4*i+2] + q4.w*S[4*i+3];
                }
                voc[t][base + lane] = oe;          // v dead: snapshots done
            }
        } else {
            #pragma unroll
            for (int t = 0; t < 32; ++t) {
                float oe = 0.0f;
                #pragma unroll
                for (int i = 0; i < 8; ++i) {
                    float4 q4 = *(const float4*)&qf[t][base + 4 * i];
                    oe += q4.x*S[4*i] + q4.y*S[4*i+1] + q4.z*S[4*i+2] + q4.w*S[4*i+3];
                }
                o0[t] = oe;
            }
        }
        // F4: S = exp(gl)*(S + ke^T v) for own k-half
        {
            const int kb = base + kh * 32;
            #pragma unroll
            for (int i = 0; i < 8; ++i) {
                float s0 = 0.0f, s1 = 0.0f, s2 = 0.0f, s3 = 0.0f;
                #pragma unroll
                for (int t = 0; t < 32; ++t) {
                    float4 k4 = *(const float4*)&kf[t][kb + 4 * i];
                    const float vt = vcol[t];
                    s0 += k4.x * vt; s1 += k4.y * vt; s2 += k4.z * vt; s3 += k4.w * vt;
                }
                S[4*i+0] = egl[kb + 4*i+0] * (S[4*i+0] + s0);
                S[4*i+1] = egl[kb + 4*i+1] * (S[4*i+1] + s1);
                S[4*i+2] = egl[kb + 4*i+2] * (S[4*i+2] + s2);
                S[4*i+3] = egl[kb + 4*i+3] * (S[4*i+3] + s3);
            }
        }
        __syncthreads();

        // F2b: kh0 finalizes o = oe0 + oe1 + o_intra, RMS-norm, into voc
        if (kh == 0) {
            #pragma unroll
            for (int t = 0; t < 32; ++t) {
                float ot = o0[t] + voc[t][base + lane];
                const float* arow = &Ats[h * 1152 + t * 36];
                #pragma unroll
                for (int s4 = 0; s4 + 4 <= t + 1; s4 += 4) {
                    float4 a4 = *(const float4*)&arow[s4];
                    ot += a4.x*vcol[s4] + a4.y*vcol[s4+1] + a4.z*vcol[s4+2] + a4.w*vcol[s4+3];
                }
                #pragma unroll
                for (int s = (t + 1) & ~3; s <= t; ++s) ot += arow[s] * vcol[s];
                float ss = ot * ot;
                #pragma unroll
                for (int off = 32; off > 0; off >>= 1) ss += __shfl_xor(ss, off, 64);
                voc[t][base + lane] = ot * rsqrtf(ss * (1.0f / 64.0f) + EPS) * gnv;
            }
        }
        __syncthreads();

        // ---- G: r = f @ Wr ; voc *= silu(r) ----
        {
            const int t0 = th * 16;
            float ar[16];
            #pragma unroll
            for (int t = 0; t < 16; ++t) ar[t] = 0.0f;
            for (int cc = 0; cc < 64; ++cc) {
                float col[17];
                #pragma unroll
                for (int i = 0; i < 4; ++i) {
                    float4 c4 = *(const float4*)&sxc[cc][t0 + 4 * i];
                    col[4*i] = c4.x; col[4*i+1] = c4.y; col[4*i+2] = c4.z; col[4*i+3] = c4.w;
                }
                col[16] = sxc[cc][t0 + 16];
                const float w0 = Wr[(2*cc)*256 + d], w1 = Wr[(2*cc+1)*256 + d];
                #pragma unroll
                for (int t = 0; t < 16; ++t) ar[t] += col[t] * w0 + col[t+1] * w1;
            }
            #pragma unroll
            for (int t = 0; t < 16; ++t) {
                const float r = ar[t];
                voc[t0 + t][d] *= r / (1.0f + __expf(-r));
            }
        }
        __syncthreads();

        // ---- H: gdec = oc @ Wo ; thread = (m2 in [0,64), 2 cols, 4 rows) ----
        {
            const int m2  = tid & 63;
            const int tg4 = tid >> 6;        // 0..7 -> rows tg4*4..+3
            float accA[4] = {0,0,0,0}, accB[4] = {0,0,0,0};
            for (int j = 0; j < 256; j += 4) {
                float wA0 = Wo[(j+0)*128 + m2],      wB0 = Wo[(j+0)*128 + m2 + 64];
                float wA1 = Wo[(j+1)*128 + m2],      wB1 = Wo[(j+1)*128 + m2 + 64];
                float wA2 = Wo[(j+2)*128 + m2],      wB2 = Wo[(j+2)*128 + m2 + 64];
                float wA3 = Wo[(j+3)*128 + m2],      wB3 = Wo[(j+3)*128 + m2 + 64];
                #pragma unroll
                for (int i = 0; i < 4; ++i) {
                    float4 o4 = *(const float4*)&voc[tg4 * 4 + i][j];
                    accA[i] += o4.x*wA0 + o4.y*wA1 + o4.z*wA2 + o4.w*wA3;
                    accB[i] += o4.x*wB0 + o4.y*wB1 + o4.z*wB2 + o4.w*wB3;
                }
            }
            #pragma unroll
            for (int i = 0; i < 4; ++i) {
                gdec[(tg4 * 4 + i) * 132 + m2]      = accA[i];
                gdec[(tg4 * 4 + i) * 132 + m2 + 64] = accB[i];
            }
        }
        __syncthreads();

        // ---- I: deconv1d (K=2) + bias + residual (from sxr) + store ----
        {
            const int o  = lane;
            const int pg = wv;               // 0..7 -> rows pg*4..+3
            const float2* ctw2 = (const float2*)ctw;   // [cin][o] -> (w_k0, w_k1)
            float acc4[4] = {0,0,0,0};
            for (int c4 = 0; c4 < 128; c4 += 4) {
                float2 w0 = ctw2[(c4+0)*64 + o];
                float2 w1 = ctw2[(c4+1)*64 + o];
                float2 w2 = ctw2[(c4+2)*64 + o];
                float2 w3 = ctw2[(c4+3)*64 + o];
                float4 r[5];
                r[0] = (pg == 0) ? *(const float4*)&gprevs[c4]
                                 : *(const float4*)&gdec[(pg*4 - 1) * 132 + c4];
                #pragma unroll
                for (int j = 0; j < 4; ++j)
                    r[j+1] = *(const float4*)&gdec[(pg*4 + j) * 132 + c4];
                #pragma unroll
                for (int i = 0; i < 4; ++i) {
                    acc4[i] += r[i+1].x*w0.x + r[i].x*w0.y
                             + r[i+1].y*w1.x + r[i].y*w1.y
                             + r[i+1].z*w2.x + r[i].z*w2.y
                             + r[i+1].w*w3.x + r[i].w*w3.y;
                }
            }
            #pragma unroll
            for (int i = 0; i < 4; ++i) {
                const int tl = pg * 4 + i;
                const int oi = cbase + o * 32768 + (l0 + tl) * PSTRIDE;
                out[oi] = acc4[i] + bias + sxr[o][tl];
            }
        }
        __syncthreads();
        if (tid < 128) gprevs[tid] = gdec[31 * 132 + tid];
    }
}

extern "C" void kernel_launch(void* const* d_in, const int* in_sizes, int n_in,
                              void* d_out, int out_size, void* d_ws, size_t ws_size,
                              hipStream_t stream)
{
    const float* x = (const float*)d_in[0];
    float* y = (float*)d_ws;     // intra output: 4*64*256*128 fp32
    float* z = (float*)d_out;

    gla_pass<128, 1><<<dim3(1024), dim3(512), 0, stream>>>(
        x, y,
        (const float*)d_in[2],  (const float*)d_in[3],  (const float*)d_in[4],
        (const float*)d_in[5],  (const float*)d_in[6],  (const float*)d_in[7],
        (const float*)d_in[8],  (const float*)d_in[9],  (const float*)d_in[10],
        (const float*)d_in[11], (const float*)d_in[12], (const float*)d_in[13]);

    gla_pass<256, 128><<<dim3(512), dim3(512), 0, stream>>>(
        y, z,
        (const float*)d_in[14], (const float*)d_in[15], (const float*)d_in[16],
        (const float*)d_in[17], (const float*)d_in[18], (const float*)d_in[19],
        (const float*)d_in[20], (const float*)d_in[21], (const float*)d_in[22],
        (const float*)d_in[23], (const float*)d_in[24], (const float*)d_in[25]);
}

// Round 6
// 7403.140 us; speedup vs baseline: 2.0595x; 2.0595x over previous
//
#include <hip/hip_runtime.h>

#define EPS 1e-5f

__device__ __forceinline__ float logsig(float z) {
    return fminf(z, 0.0f) - log1pf(__expf(-fabsf(z)));
}

// One block = one sequence. 512 threads = 8 waves.
// Head h = wave&3; k-half kh = wave>>2 (kh0 holds S rows 0..31, kh1 rows 32..63).
// PSTRIDE==1  : intra pass (seq over q, SLEN=128); PSTRIDE==128: inter pass (SLEN=256)
// LDS = 155.5 KB pins occupancy at 1 block/CU (2 waves/EU). The backend caps
// 512-thread kernels at 128 VGPRs by default (R4/R5: byte-identical binaries for
// launch_bounds (512,1) vs (512,2)); amdgpu_waves_per_eu(2,2) states the true
// occupancy so the RA can budget 256, and the F-stage choreography below keeps
// peak live ~<100 regs so we fit even if the cap stays.
template<int SLEN, int PSTRIDE>
__global__ __launch_bounds__(512)
__attribute__((amdgpu_waves_per_eu(2, 2)))
void gla_pass(const float* __restrict__ src, float* __restrict__ out,
              const float* __restrict__ gamma, const float* __restrict__ beta,
              const float* __restrict__ Wq, const float* __restrict__ Wk,
              const float* __restrict__ Wv, const float* __restrict__ Wg1,
              const float* __restrict__ Wg2, const float* __restrict__ Wr,
              const float* __restrict__ gn, const float* __restrict__ Wo,
              const float* __restrict__ ctw, const float* __restrict__ ctb)
{
    constexpr int NC = SLEN / 32;
    constexpr int L  = SLEN - 1;

    __shared__ __align__(16) float sxc[64][36];   // LN'd slab window (33 cols used)
    __shared__ __align__(16) float sxr[64][32];   // raw slab (residual source)
    __shared__ __align__(16) float qf[32][256];   // q*Dk^-0.5 * exp(gc)
    __shared__ __align__(16) float kf[32][256];   // k * exp(-gc)
    __shared__ __align__(16) float voc[32][256];  // v -> oe1 partial -> o -> o*silu(r)
    __shared__ __align__(16) float uni[8832];     // Ats[4][32][36] + gdec[32][132]
    __shared__ __align__(16) float fw1t[32][36];  // (f @ Wg1)^T : fw1t[m][t]
    __shared__ __align__(16) float gprevs[128];   // deconv carry row
    __shared__ float egl[256];                    // exp(chunk-total gate)
    __shared__ float sgam[64], sbet[64];
    __shared__ float smu[33], sinv[33];
    __shared__ float gcarry[256];                 // gate cumsum carry (t=0..15 total)

    float* const Ats  = uni;          // h*1152 + t*36 + s
    float* const gdec = uni + 4608;   // row*132 + c

    const int tid  = threadIdx.x;
    const int lane = tid & 63;
    const int wv   = tid >> 6;        // 0..7
    const int h    = wv & 3;          // head
    const int kh   = wv >> 2;         // k-half
    const int d    = tid & 255;       // column for t-split stages
    const int th   = (tid >> 8) & 1;  // t-half (rows th*16 .. th*16+15); th == kh
    const int n    = blockIdx.x;

    int b, fixedoff;
    if constexpr (PSTRIDE == 1) { b = n >> 8; fixedoff = (n & 255) * 128; }
    else                        { b = n >> 7; fixedoff = (n & 127); }
    const int cbase = (b * 64) * 32768 + fixedoff;

    if (tid < 64)  { sgam[tid] = gamma[tid]; sbet[tid] = beta[tid]; }
    if (tid < 128) gprevs[tid] = 0.0f;

    float S[32];
    #pragma unroll
    for (int k = 0; k < 32; ++k) S[k] = 0.0f;

    const float gnv  = gn[h * 64 + lane];
    const float bias = ctb[lane];

    for (int ch = 0; ch < NC; ++ch) {
        const int l0 = ch * 32;
        __syncthreads();

        // ---- A: load 33-col slab window (raw copy kept for residual) ----
        for (int idx = tid; idx < 64 * 33; idx += 512) {
            int cc = idx / 33;
            int i  = idx - cc * 33;
            int p  = l0 + i; if (p > SLEN - 1) p = SLEN - 1;
            float x = src[cbase + cc * 32768 + p * PSTRIDE];
            sxc[cc][i] = x;
            if (i < 32) sxr[cc][i] = x;
        }
        __syncthreads();

        // ---- B1: per-column LN stats ----
        if (tid < 33) {
            float s1 = 0.0f, s2 = 0.0f;
            for (int cc = 0; cc < 64; ++cc) { float x = sxc[cc][tid]; s1 += x; s2 += x * x; }
            float mu = s1 * (1.0f / 64.0f);
            float var = s2 * (1.0f / 64.0f) - mu * mu;
            smu[tid]  = mu;
            sinv[tid] = rsqrtf(fmaxf(var, 0.0f) + EPS);
        }
        __syncthreads();
        // ---- B2: normalize in place (parallel) ----
        for (int idx = tid; idx < 64 * 33; idx += 512) {
            int cc = idx / 33;
            int i  = idx - cc * 33;
            sxc[cc][i] = (sxc[cc][i] - smu[i]) * sinv[i] * sgam[cc] + sbet[cc];
        }
        __syncthreads();

        // ---- gate p1: fw1t[m][t] ----
        {
            const int m = tid & 31, tg2 = tid >> 5;   // tg2 in [0,16)
            float a0 = 0.0f, a1 = 0.0f;
            for (int cc = 0; cc < 64; ++cc) {
                const float w0 = Wg1[(2*cc)*32 + m], w1 = Wg1[(2*cc+1)*32 + m];
                a0 += sxc[cc][tg2]      * w0 + sxc[cc][tg2 + 1]  * w1;
                a1 += sxc[cc][tg2 + 16] * w0 + sxc[cc][tg2 + 17] * w1;
            }
            fw1t[m][tg2] = a0; fw1t[m][tg2 + 16] = a1;
        }
        __syncthreads();

        // ---- gate p2: per (col d, t-half) cumsum with carry -> erun/egl ----
        float erunp[16], erunm[16];   // exp(+gc), exp(-gc) for own t-half
        {
            const int t0 = th * 16;
            float acc2[16];
            #pragma unroll
            for (int t = 0; t < 16; ++t) acc2[t] = 0.0f;
            for (int mm = 0; mm < 32; ++mm) {
                const float w = Wg2[mm * 256 + d];
                #pragma unroll
                for (int i = 0; i < 4; ++i) {
                    float4 f4 = *(const float4*)&fw1t[mm][t0 + 4 * i];
                    acc2[4*i+0] += f4.x * w; acc2[4*i+1] += f4.y * w;
                    acc2[4*i+2] += f4.z * w; acc2[4*i+3] += f4.w * w;
                }
            }
            float r = 0.0f;
            #pragma unroll
            for (int t = 0; t < 16; ++t) {
                if ((l0 + t0 + t) < L) r += logsig(acc2[t]) * (1.0f / 32.0f);
                acc2[t] = r;                    // reuse as cumsum store
            }
            if (th == 0) gcarry[d] = r;
            __syncthreads();
            const float c = (th == 0) ? 0.0f : gcarry[d];
            #pragma unroll
            for (int t = 0; t < 16; ++t) {
                float run = c + acc2[t];
                erunp[t] = __expf(run);
                erunm[t] = __expf(-run);
            }
            if (th == 1) egl[d] = erunp[15];
        }

        // ---- C: projections; (q,k) fused then v; gate folded at store ----
        {
            const int t0 = th * 16;
            float aq[16], ak[16];
            #pragma unroll
            for (int t = 0; t < 16; ++t) { aq[t] = 0.0f; ak[t] = 0.0f; }
            for (int cc = 0; cc < 64; ++cc) {
                float col[17];
                #pragma unroll
                for (int i = 0; i < 4; ++i) {
                    float4 c4 = *(const float4*)&sxc[cc][t0 + 4 * i];
                    col[4*i] = c4.x; col[4*i+1] = c4.y; col[4*i+2] = c4.z; col[4*i+3] = c4.w;
                }
                col[16] = sxc[cc][t0 + 16];
                const float wq0 = Wq[(2*cc)*256 + d], wq1 = Wq[(2*cc+1)*256 + d];
                const float wk0 = Wk[(2*cc)*256 + d], wk1 = Wk[(2*cc+1)*256 + d];
                #pragma unroll
                for (int t = 0; t < 16; ++t) {
                    aq[t] += col[t] * wq0 + col[t+1] * wq1;
                    ak[t] += col[t] * wk0 + col[t+1] * wk1;
                }
            }
            #pragma unroll
            for (int t = 0; t < 16; ++t) {
                bool valid = (l0 + t0 + t) < L;
                qf[t0 + t][d] = valid ? aq[t] * 0.125f * erunp[t] : 0.0f;
                kf[t0 + t][d] = valid ? ak[t] * erunm[t] : 0.0f;
            }
        }
        {
            const int t0 = th * 16;
            float av[16];
            #pragma unroll
            for (int t = 0; t < 16; ++t) av[t] = 0.0f;
            for (int cc = 0; cc < 64; ++cc) {
                float col[17];
                #pragma unroll
                for (int i = 0; i < 4; ++i) {
                    float4 c4 = *(const float4*)&sxc[cc][t0 + 4 * i];
                    col[4*i] = c4.x; col[4*i+1] = c4.y; col[4*i+2] = c4.z; col[4*i+3] = c4.w;
                }
                col[16] = sxc[cc][t0 + 16];
                const float wv0 = Wv[(2*cc)*256 + d], wv1 = Wv[(2*cc+1)*256 + d];
                #pragma unroll
                for (int t = 0; t < 16; ++t) av[t] += col[t] * wv0 + col[t+1] * wv1;
            }
            #pragma unroll
            for (int t = 0; t < 16; ++t)
                voc[t0 + t][d] = ((l0 + t0 + t) < L) ? av[t] : 0.0f;
        }
        __syncthreads();

        // ---- F: attention; 2 waves per head ----
        const int base = h * 64;
        float vcol[32];
        #pragma unroll
        for (int t = 0; t < 32; ++t) vcol[t] = voc[t][base + lane];

        // F1: triangular scores, 128 lanes per head
        for (int pi = lane + 64 * kh; pi < 528; pi += 128) {
            float fpi = (float)pi;
            int t = (int)((sqrtf(8.0f * fpi + 1.0f) - 1.0f) * 0.5f);
            if (((t + 1) * (t + 2)) / 2 <= pi) ++t;
            if ((t * (t + 1)) / 2 > pi) --t;
            int s = pi - (t * (t + 1)) / 2;
            float a = 0.0f;
            #pragma unroll
            for (int ii = 0; ii < 16; ++ii) {
                int i = (ii + lane) & 15;
                float4 q4 = *(const float4*)&qf[t][base + 4 * i];
                float4 k4 = *(const float4*)&kf[s][base + 4 * i];
                a += q4.x*k4.x + q4.y*k4.y + q4.z*k4.z + q4.w*k4.w;
            }
            Ats[h * 1152 + t * 36 + s] = a;
        }
        __syncthreads();   // A: Ats ready; all vcol snapshots done (voc dead as v)

        // F2a: kh1 writes o_inter partial (vs pre-update S rows 32..63) into voc
        if (kh == 1) {
            #pragma unroll
            for (int t = 0; t < 32; ++t) {
                float oe = 0.0f;
                #pragma unroll
                for (int i = 0; i < 8; ++i) {
                    float4 q4 = *(const float4*)&qf[t][base + 32 + 4 * i];
                    oe += q4.x*S[4*i] + q4.y*S[4*i+1] + q4.z*S[4*i+2] + q4.w*S[4*i+3];
                }
                voc[t][base + lane] = oe;
            }
        }
        __syncthreads();   // B: oe1 partials in voc

        if (kh == 0) {
            // F2b: o = oe0 + oe1 + o_intra, RMS-norm, final o into voc (no o0[] array)
            #pragma unroll
            for (int t = 0; t < 32; ++t) {
                float ot = voc[t][base + lane];
                #pragma unroll
                for (int i = 0; i < 8; ++i) {
                    float4 q4 = *(const float4*)&qf[t][base + 4 * i];
                    ot += q4.x*S[4*i] + q4.y*S[4*i+1] + q4.z*S[4*i+2] + q4.w*S[4*i+3];
                }
                const float* arow = &Ats[h * 1152 + t * 36];
                #pragma unroll
                for (int s4 = 0; s4 + 4 <= t + 1; s4 += 4) {
                    float4 a4 = *(const float4*)&arow[s4];
                    ot += a4.x*vcol[s4] + a4.y*vcol[s4+1] + a4.z*vcol[s4+2] + a4.w*vcol[s4+3];
                }
                #pragma unroll
                for (int s = (t + 1) & ~3; s <= t; ++s) ot += arow[s] * vcol[s];
                float ss = ot * ot;
                #pragma unroll
                for (int off = 32; off > 0; off >>= 1) ss += __shfl_xor(ss, off, 64);
                voc[t][base + lane] = ot * rsqrtf(ss * (1.0f / 64.0f) + EPS) * gnv;
            }
        } else {
            // kh1: F4 state update rows 32..63 (overlaps kh0's F2b)
            const int kb = base + 32;
            #pragma unroll
            for (int i = 0; i < 8; ++i) {
                float s0 = 0.0f, s1 = 0.0f, s2 = 0.0f, s3 = 0.0f;
                #pragma unroll
                for (int t = 0; t < 32; ++t) {
                    float4 k4 = *(const float4*)&kf[t][kb + 4 * i];
                    const float vt = vcol[t];
                    s0 += k4.x * vt; s1 += k4.y * vt; s2 += k4.z * vt; s3 += k4.w * vt;
                }
                S[4*i+0] = egl[kb + 4*i+0] * (S[4*i+0] + s0);
                S[4*i+1] = egl[kb + 4*i+1] * (S[4*i+1] + s1);
                S[4*i+2] = egl[kb + 4*i+2] * (S[4*i+2] + s2);
                S[4*i+3] = egl[kb + 4*i+3] * (S[4*i+3] + s3);
            }
        }
        __syncthreads();   // C: final o in voc; kh0 may now update S

        if (kh == 0) {
            // F4 state update rows 0..31 (overlaps kh1's half of G)
            const int kb = base;
            #pragma unroll
            for (int i = 0; i < 8; ++i) {
                float s0 = 0.0f, s1 = 0.0f, s2 = 0.0f, s3 = 0.0f;
                #pragma unroll
                for (int t = 0; t < 32; ++t) {
                    float4 k4 = *(const float4*)&kf[t][kb + 4 * i];
                    const float vt = vcol[t];
                    s0 += k4.x * vt; s1 += k4.y * vt; s2 += k4.z * vt; s3 += k4.w * vt;
                }
                S[4*i+0] = egl[kb + 4*i+0] * (S[4*i+0] + s0);
                S[4*i+1] = egl[kb + 4*i+1] * (S[4*i+1] + s1);
                S[4*i+2] = egl[kb + 4*i+2] * (S[4*i+2] + s2);
                S[4*i+3] = egl[kb + 4*i+3] * (S[4*i+3] + s3);
            }
        }

        // ---- G: r = f @ Wr ; voc *= silu(r) ----
        {
            const int t0 = th * 16;
            float ar[16];
            #pragma unroll
            for (int t = 0; t < 16; ++t) ar[t] = 0.0f;
            for (int cc = 0; cc < 64; ++cc) {
                float col[17];
                #pragma unroll
                for (int i = 0; i < 4; ++i) {
                    float4 c4 = *(const float4*)&sxc[cc][t0 + 4 * i];
                    col[4*i] = c4.x; col[4*i+1] = c4.y; col[4*i+2] = c4.z; col[4*i+3] = c4.w;
                }
                col[16] = sxc[cc][t0 + 16];
                const float w0 = Wr[(2*cc)*256 + d], w1 = Wr[(2*cc+1)*256 + d];
                #pragma unroll
                for (int t = 0; t < 16; ++t) ar[t] += col[t] * w0 + col[t+1] * w1;
            }
            #pragma unroll
            for (int t = 0; t < 16; ++t) {
                const float r = ar[t];
                voc[t0 + t][d] *= r / (1.0f + __expf(-r));
            }
        }
        __syncthreads();

        // ---- H: gdec = oc @ Wo ; thread = (m2 in [0,64), 2 cols, 4 rows) ----
        {
            const int m2  = tid & 63;
            const int tg4 = tid >> 6;        // 0..7 -> rows tg4*4..+3
            float accA[4] = {0,0,0,0}, accB[4] = {0,0,0,0};
            for (int j = 0; j < 256; j += 4) {
                float wA0 = Wo[(j+0)*128 + m2],      wB0 = Wo[(j+0)*128 + m2 + 64];
                float wA1 = Wo[(j+1)*128 + m2],      wB1 = Wo[(j+1)*128 + m2 + 64];
                float wA2 = Wo[(j+2)*128 + m2],      wB2 = Wo[(j+2)*128 + m2 + 64];
                float wA3 = Wo[(j+3)*128 + m2],      wB3 = Wo[(j+3)*128 + m2 + 64];
                #pragma unroll
                for (int i = 0; i < 4; ++i) {
                    float4 o4 = *(const float4*)&voc[tg4 * 4 + i][j];
                    accA[i] += o4.x*wA0 + o4.y*wA1 + o4.z*wA2 + o4.w*wA3;
                    accB[i] += o4.x*wB0 + o4.y*wB1 + o4.z*wB2 + o4.w*wB3;
                }
            }
            #pragma unroll
            for (int i = 0; i < 4; ++i) {
                gdec[(tg4 * 4 + i) * 132 + m2]      = accA[i];
                gdec[(tg4 * 4 + i) * 132 + m2 + 64] = accB[i];
            }
        }
        __syncthreads();

        // ---- I: deconv1d (K=2) + bias + residual (from sxr) + store ----
        {
            const int o  = lane;
            const int pg = wv;               // 0..7 -> rows pg*4..+3
            const float2* ctw2 = (const float2*)ctw;   // [cin][o] -> (w_k0, w_k1)
            float acc4[4] = {0,0,0,0};
            for (int c4 = 0; c4 < 128; c4 += 4) {
                float2 w0 = ctw2[(c4+0)*64 + o];
                float2 w1 = ctw2[(c4+1)*64 + o];
                float2 w2 = ctw2[(c4+2)*64 + o];
                float2 w3 = ctw2[(c4+3)*64 + o];
                float4 r[5];
                r[0] = (pg == 0) ? *(const float4*)&gprevs[c4]
                                 : *(const float4*)&gdec[(pg*4 - 1) * 132 + c4];
                #pragma unroll
                for (int j = 0; j < 4; ++j)
                    r[j+1] = *(const float4*)&gdec[(pg*4 + j) * 132 + c4];
                #pragma unroll
                for (int i = 0; i < 4; ++i) {
                    acc4[i] += r[i+1].x*w0.x + r[i].x*w0.y
                             + r[i+1].y*w1.x + r[i].y*w1.y
                             + r[i+1].z*w2.x + r[i].z*w2.y
                             + r[i+1].w*w3.x + r[i].w*w3.y;
                }
            }
            #pragma unroll
            for (int i = 0; i < 4; ++i) {
                const int tl = pg * 4 + i;
                const int oi = cbase + o * 32768 + (l0 + tl) * PSTRIDE;
                out[oi] = acc4[i] + bias + sxr[o][tl];
            }
        }
        __syncthreads();
        if (tid < 128) gprevs[tid] = gdec[31 * 132 + tid];
    }
}

extern "C" void kernel_launch(void* const* d_in, const int* in_sizes, int n_in,
                              void* d_out, int out_size, void* d_ws, size_t ws_size,
                              hipStream_t stream)
{
    const float* x = (const float*)d_in[0];
    float* y = (float*)d_ws;     // intra output: 4*64*256*128 fp32
    float* z = (float*)d_out;

    gla_pass<128, 1><<<dim3(1024), dim3(512), 0, stream>>>(
        x, y,
        (const float*)d_in[2],  (const float*)d_in[3],  (const float*)d_in[4],
        (const float*)d_in[5],  (const float*)d_in[6],  (const float*)d_in[7],
        (const float*)d_in[8],  (const float*)d_in[9],  (const float*)d_in[10],
        (const float*)d_in[11], (const float*)d_in[12], (const float*)d_in[13]);

    gla_pass<256, 128><<<dim3(512), dim3(512), 0, stream>>>(
        y, z,
        (const float*)d_in[14], (const float*)d_in[15], (const float*)d_in[16],
        (const float*)d_in[17], (const float*)d_in[18], (const float*)d_in[19],
        (const float*)d_in[20], (const float*)d_in[21], (const float*)d_in[22],
        (const float*)d_in[23], (const float*)d_in[24], (const float*)d_in[25]);
}